// Round 1
// baseline (345.658 us; speedup 1.0000x reference)
//
#include <hip/hip_runtime.h>
#include <hip/hip_bf16.h>

typedef __hip_bfloat16 bf16;
typedef __attribute__((ext_vector_type(8))) short bf16x8;
typedef __attribute__((ext_vector_type(4))) float f32x4;

#define MFMA_BF16(a, b, c) __builtin_amdgcn_mfma_f32_16x16x32_bf16((a), (b), (c), 0, 0, 0)

static constexpr int B_  = 2;
static constexpr int S_  = 2048;
static constexpr int DM_ = 1024;
static constexpr int H_  = 16;
static constexpr int D_  = 64;
static constexpr int M_  = B_ * S_;   // 4096 rows for all GEMMs

__device__ __forceinline__ void load16(const void* g, void* l) {
  __builtin_amdgcn_global_load_lds(
      (const __attribute__((address_space(1))) void*)g,
      (__attribute__((address_space(3))) void*)l, 16, 0, 0);
}

// ---------------- prep kernels ----------------

__global__ void cvt_f32_bf16_kernel(const float* __restrict__ in,
                                    bf16* __restrict__ out, int n4) {
  int i = blockIdx.x * blockDim.x + threadIdx.x;
  if (i >= n4) return;
  float4 v = ((const float4*)in)[i];
  ushort4 u;
  u.x = __builtin_bit_cast(unsigned short, __float2bfloat16(v.x));
  u.y = __builtin_bit_cast(unsigned short, __float2bfloat16(v.y));
  u.z = __builtin_bit_cast(unsigned short, __float2bfloat16(v.z));
  u.w = __builtin_bit_cast(unsigned short, __float2bfloat16(v.w));
  ((ushort4*)out)[i] = u;
}

// out[n][k] = (bf16) in[k][n], both 1024x1024
__global__ void transpose_cvt_kernel(const float* __restrict__ in,
                                     bf16* __restrict__ out) {
  __shared__ float t[32][33];
  int tx = threadIdx.x & 31;
  int ty = threadIdx.x >> 5;  // 0..7
  int r0 = blockIdx.y * 32;
  int c0 = blockIdx.x * 32;
#pragma unroll
  for (int yy = 0; yy < 32; yy += 8)
    t[ty + yy][tx] = in[(size_t)(r0 + ty + yy) * DM_ + c0 + tx];
  __syncthreads();
#pragma unroll
  for (int yy = 0; yy < 32; yy += 8)
    out[(size_t)(c0 + ty + yy) * DM_ + r0 + tx] = __float2bfloat16(t[tx][ty + yy]);
}

// ---------------- GEMM: C = A(MxK) * Bt(NxK)^T + bias ----------------
// MODE 0: store bf16 to (B,H,S,D)   (Q/K projections)
// MODE 1: store bf16 to (B,H,D,S)   (V projection, pre-transposed)
// MODE 2: store fp32 to (M, 1024)   (output projection)
template <int MODE>
__global__ __launch_bounds__(256) void gemm_bt_kernel(
    const bf16* __restrict__ A, const bf16* __restrict__ Bt,
    const float* __restrict__ bias, void* __restrict__ out, int K) {
  __shared__ bf16 As[128 * 32];
  __shared__ bf16 Bs[128 * 32];
  const int tid = threadIdx.x;
  const int wid = tid >> 6, lane = tid & 63;
  const int g = lane >> 4, c = lane & 15;
  const int wr = wid >> 1, wc = wid & 1;  // wave = 64x64 subtile
  const int bm = blockIdx.x, bn = blockIdx.y;

  f32x4 acc[4][4] = {};

  const char* Ag = (const char*)(A + (size_t)bm * 128 * K);
  const char* Bg = (const char*)(Bt + (size_t)bn * 128 * K);
  const int f0 = tid * 16, f1 = f0 + 4096;
  const int r0 = f0 >> 6, cb0 = f0 & 63;
  const int r1 = f1 >> 6;
  const size_t rowbytes = (size_t)K * 2;

  for (int kt = 0; kt < K / 32; ++kt) {
    const size_t koff = (size_t)kt * 64;  // 32 bf16 = 64B
    load16(Ag + (size_t)r0 * rowbytes + koff + cb0, (char*)As + f0);
    load16(Ag + (size_t)r1 * rowbytes + koff + cb0, (char*)As + f1);
    load16(Bg + (size_t)r0 * rowbytes + koff + cb0, (char*)Bs + f0);
    load16(Bg + (size_t)r1 * rowbytes + koff + cb0, (char*)Bs + f1);
    __syncthreads();
    bf16x8 af[4], bfr[4];
#pragma unroll
    for (int mi = 0; mi < 4; ++mi)
      af[mi] = *(const bf16x8*)&As[(wr * 64 + mi * 16 + c) * 32 + g * 8];
#pragma unroll
    for (int ni = 0; ni < 4; ++ni)
      bfr[ni] = *(const bf16x8*)&Bs[(wc * 64 + ni * 16 + c) * 32 + g * 8];
#pragma unroll
    for (int mi = 0; mi < 4; ++mi)
#pragma unroll
      for (int ni = 0; ni < 4; ++ni)
        acc[mi][ni] = MFMA_BF16(af[mi], bfr[ni], acc[mi][ni]);
    __syncthreads();
  }

  // epilogue: C row = (lane>>4)*4 + r, col = lane&15  (per 16x16 frag)
#pragma unroll
  for (int ni = 0; ni < 4; ++ni) {
    const int n_g = bn * 128 + wc * 64 + ni * 16 + c;
    const float bv = bias[n_g];
#pragma unroll
    for (int mi = 0; mi < 4; ++mi) {
#pragma unroll
      for (int r = 0; r < 4; ++r) {
        const int m_g = bm * 128 + wr * 64 + mi * 16 + g * 4 + r;
        const float val = acc[mi][ni][r] + bv;
        if constexpr (MODE == 2) {
          ((float*)out)[(size_t)m_g * DM_ + n_g] = val;
        } else {
          const int b = m_g >> 11, s = m_g & (S_ - 1);
          const int h = n_g >> 6, d = n_g & (D_ - 1);
          size_t idx;
          if constexpr (MODE == 0)
            idx = (((size_t)(b * H_ + h)) * S_ + s) * D_ + d;
          else
            idx = (((size_t)(b * H_ + h)) * D_ + d) * S_ + s;
          ((bf16*)out)[idx] = __float2bfloat16(val);
        }
      }
    }
  }
}

// ---------------- flash attention ----------------
// Q,K: (B,H,S,D) bf16 ; Vt: (B,H,D,S) bf16 ; Aout: (B,S,H*D) bf16
// block = 256 thr (4 waves); block handles 64 Q rows of one (b,h); wave = 16 rows.
__global__ __launch_bounds__(256) void flash_attn_kernel(
    const bf16* __restrict__ Q, const bf16* __restrict__ Kg,
    const bf16* __restrict__ Vt, bf16* __restrict__ Aout) {
  __shared__ bf16 P_lds[4][16][72];  // per-wave P tile, padded stride (144B rows)
  const int qt = blockIdx.x;   // 0..31 (Q tile of 64 rows)
  const int bh = blockIdx.y;   // 0..31
  const int wid = threadIdx.x >> 6;
  const int lane = threadIdx.x & 63;
  const int g = lane >> 4, c = lane & 15;

  const bf16* Qp = Q + ((size_t)bh * S_ + qt * 64 + wid * 16) * D_;
  bf16x8 qf[2];
  qf[0] = *(const bf16x8*)&Qp[c * D_ + g * 8];
  qf[1] = *(const bf16x8*)&Qp[c * D_ + 32 + g * 8];

  f32x4 o[4] = {};
  float mrun[4], lrun[4];
#pragma unroll
  for (int r = 0; r < 4; ++r) { mrun[r] = -__builtin_inff(); lrun[r] = 0.f; }
  const int row0 = qt * 64 + wid * 16 + g * 4;

  for (int kv = 0; kv <= qt; ++kv) {
    const bf16* Kp = Kg + ((size_t)bh * S_ + kv * 64) * D_;
    f32x4 s[4] = {};
#pragma unroll
    for (int n = 0; n < 4; ++n) {
      bf16x8 kf0 = *(const bf16x8*)&Kp[(n * 16 + c) * D_ + g * 8];
      bf16x8 kf1 = *(const bf16x8*)&Kp[(n * 16 + c) * D_ + 32 + g * 8];
      s[n] = MFMA_BF16(qf[0], kf0, s[n]);
      s[n] = MFMA_BF16(qf[1], kf1, s[n]);
    }
    float p[4][4];
    const bool diag = (kv == qt);
#pragma unroll
    for (int n = 0; n < 4; ++n) {
      const int col = kv * 64 + n * 16 + c;
#pragma unroll
      for (int r = 0; r < 4; ++r) {
        float v = s[n][r] * 0.125f;  // 1/sqrt(64)
        if (diag && col > row0 + r) v = -__builtin_inff();
        p[n][r] = v;
      }
    }
    // row max across the 16 lanes of each group (cols) -- wave-parallel
    float mt[4], lt[4];
#pragma unroll
    for (int r = 0; r < 4; ++r)
      mt[r] = fmaxf(fmaxf(p[0][r], p[1][r]), fmaxf(p[2][r], p[3][r]));
#pragma unroll
    for (int d2 = 1; d2 < 16; d2 <<= 1)
#pragma unroll
      for (int r = 0; r < 4; ++r) mt[r] = fmaxf(mt[r], __shfl_xor(mt[r], d2, 64));

    float mnew[4], scalef[4];
#pragma unroll
    for (int r = 0; r < 4; ++r) {
      mnew[r] = fmaxf(mrun[r], mt[r]);
      scalef[r] = __expf(mrun[r] - mnew[r]);  // exp(-inf)=0 on first tile
      lt[r] = 0.f;
    }
#pragma unroll
    for (int n = 0; n < 4; ++n)
#pragma unroll
      for (int r = 0; r < 4; ++r) {
        p[n][r] = __expf(p[n][r] - mnew[r]);  // masked -> exp(-inf)=0
        lt[r] += p[n][r];
      }
#pragma unroll
    for (int d2 = 1; d2 < 16; d2 <<= 1)
#pragma unroll
      for (int r = 0; r < 4; ++r) lt[r] += __shfl_xor(lt[r], d2, 64);
#pragma unroll
    for (int r = 0; r < 4; ++r) {
      lrun[r] = lrun[r] * scalef[r] + lt[r];
      mrun[r] = mnew[r];
    }
#pragma unroll
    for (int n = 0; n < 4; ++n)
#pragma unroll
      for (int r = 0; r < 4; ++r) o[n][r] *= scalef[r];

    // P (C-layout) -> LDS -> A-layout fragments (wave-private, no barrier)
#pragma unroll
    for (int n = 0; n < 4; ++n)
#pragma unroll
      for (int r = 0; r < 4; ++r)
        P_lds[wid][g * 4 + r][n * 16 + c] = __float2bfloat16(p[n][r]);

    const bf16* Vp = Vt + (size_t)bh * D_ * S_ + kv * 64;
#pragma unroll
    for (int kk = 0; kk < 2; ++kk) {
      bf16x8 pf = *(const bf16x8*)&P_lds[wid][c][kk * 32 + g * 8];
#pragma unroll
      for (int n = 0; n < 4; ++n) {
        bf16x8 vf = *(const bf16x8*)&Vp[(size_t)(n * 16 + c) * S_ + kk * 32 + g * 8];
        o[n] = MFMA_BF16(pf, vf, o[n]);
      }
    }
  }

  const int b = bh >> 4, h = bh & (H_ - 1);
  float inv[4];
#pragma unroll
  for (int r = 0; r < 4; ++r) inv[r] = 1.f / lrun[r];
#pragma unroll
  for (int n = 0; n < 4; ++n)
#pragma unroll
    for (int r = 0; r < 4; ++r) {
      const size_t row = (size_t)b * S_ + qt * 64 + wid * 16 + g * 4 + r;
      Aout[row * (H_ * D_) + h * D_ + n * 16 + c] = __float2bfloat16(o[n][r] * inv[r]);
    }
}

// ---------------- launcher ----------------

extern "C" void kernel_launch(void* const* d_in, const int* in_sizes, int n_in,
                              void* d_out, int out_size, void* d_ws, size_t ws_size,
                              hipStream_t stream) {
  (void)in_sizes; (void)n_in; (void)out_size; (void)ws_size;
  const float* x  = (const float*)d_in[0];
  const float* Wq = (const float*)d_in[1];
  const float* bq = (const float*)d_in[2];
  const float* Wk = (const float*)d_in[3];
  const float* bk = (const float*)d_in[4];
  const float* Wv = (const float*)d_in[5];
  const float* bv = (const float*)d_in[6];
  const float* Wo = (const float*)d_in[7];
  const float* bo = (const float*)d_in[8];
  float* out = (float*)d_out;

  char* ws = (char*)d_ws;
  bf16* xb  = (bf16*)(ws);                    // 8 MB  (4096x1024 bf16)
  bf16* Wqt = (bf16*)(ws + (8u << 20));       // 2 MB each
  bf16* Wkt = (bf16*)(ws + (10u << 20));
  bf16* Wvt = (bf16*)(ws + (12u << 20));
  bf16* Wot = (bf16*)(ws + (14u << 20));
  bf16* Qb  = (bf16*)(ws + (16u << 20));      // 8 MB  (B,H,S,D)
  bf16* Kb  = (bf16*)(ws + (24u << 20));      // 8 MB
  bf16* Vtb = (bf16*)(ws + (32u << 20));      // 8 MB  (B,H,D,S)
  bf16* Ab  = xb;  // attention out reuses xb (xb dead after V projection)

  cvt_f32_bf16_kernel<<<4096, 256, 0, stream>>>(x, xb, (M_ * DM_) / 4);
  transpose_cvt_kernel<<<dim3(32, 32), 256, 0, stream>>>(Wq, Wqt);
  transpose_cvt_kernel<<<dim3(32, 32), 256, 0, stream>>>(Wk, Wkt);
  transpose_cvt_kernel<<<dim3(32, 32), 256, 0, stream>>>(Wv, Wvt);
  transpose_cvt_kernel<<<dim3(32, 32), 256, 0, stream>>>(Wo, Wot);

  gemm_bt_kernel<0><<<dim3(32, 8), 256, 0, stream>>>(xb, Wqt, bq, (void*)Qb, DM_);
  gemm_bt_kernel<0><<<dim3(32, 8), 256, 0, stream>>>(xb, Wkt, bk, (void*)Kb, DM_);
  gemm_bt_kernel<1><<<dim3(32, 8), 256, 0, stream>>>(xb, Wvt, bv, (void*)Vtb, DM_);

  flash_attn_kernel<<<dim3(32, 32), 256, 0, stream>>>(Qb, Kb, Vtb, Ab);

  gemm_bt_kernel<2><<<dim3(32, 8), 256, 0, stream>>>(Ab, Wot, bo, (void*)out, DM_);
}

// Round 2
// 255.966 us; speedup vs baseline: 1.3504x; 1.3504x over previous
//
#include <hip/hip_runtime.h>
#include <hip/hip_bf16.h>

typedef __hip_bfloat16 bf16;
typedef __attribute__((ext_vector_type(8))) short bf16x8;
typedef __attribute__((ext_vector_type(4))) float f32x4;

#define MFMA_BF16(a, b, c) __builtin_amdgcn_mfma_f32_16x16x32_bf16((a), (b), (c), 0, 0, 0)

static constexpr int B_  = 2;
static constexpr int S_  = 2048;
static constexpr int DM_ = 1024;
static constexpr int H_  = 16;
static constexpr int D_  = 64;
static constexpr int M_  = B_ * S_;   // 4096 rows for all GEMMs

__device__ __forceinline__ void load16(const void* g, void* l) {
  __builtin_amdgcn_global_load_lds(
      (const __attribute__((address_space(1))) void*)g,
      (__attribute__((address_space(3))) void*)l, 16, 0, 0);
}

// ---------------- prep kernels ----------------

__global__ void cvt_f32_bf16_kernel(const float* __restrict__ in,
                                    bf16* __restrict__ out, int n4) {
  int i = blockIdx.x * blockDim.x + threadIdx.x;
  if (i >= n4) return;
  float4 v = ((const float4*)in)[i];
  ushort4 u;
  u.x = __builtin_bit_cast(unsigned short, __float2bfloat16(v.x));
  u.y = __builtin_bit_cast(unsigned short, __float2bfloat16(v.y));
  u.z = __builtin_bit_cast(unsigned short, __float2bfloat16(v.z));
  u.w = __builtin_bit_cast(unsigned short, __float2bfloat16(v.w));
  ((ushort4*)out)[i] = u;
}

// out[n][k] = (bf16) in[k][n], both 1024x1024
__global__ void transpose_cvt_kernel(const float* __restrict__ in,
                                     bf16* __restrict__ out) {
  __shared__ float t[32][33];
  int tx = threadIdx.x & 31;
  int ty = threadIdx.x >> 5;  // 0..7
  int r0 = blockIdx.y * 32;
  int c0 = blockIdx.x * 32;
#pragma unroll
  for (int yy = 0; yy < 32; yy += 8)
    t[ty + yy][tx] = in[(size_t)(r0 + ty + yy) * DM_ + c0 + tx];
  __syncthreads();
#pragma unroll
  for (int yy = 0; yy < 32; yy += 8)
    out[(size_t)(c0 + ty + yy) * DM_ + r0 + tx] = __float2bfloat16(t[tx][ty + yy]);
}

// ---------------- GEMM: C = A(MxK) * Bt(NxK)^T + bias ----------------
// MODE 0: store bf16 to (B,H,S,D)   (Q/K projections)
// MODE 1: store bf16 to (B,H,D,S)   (V projection, pre-transposed)
// MODE 2: store fp32 to (M, 1024)   (output projection)
template <int MODE>
__global__ __launch_bounds__(256) void gemm_bt_kernel(
    const bf16* __restrict__ A, const bf16* __restrict__ Bt,
    const float* __restrict__ bias, void* __restrict__ out, int K) {
  __shared__ bf16 As[128 * 32];
  __shared__ bf16 Bs[128 * 32];
  const int tid = threadIdx.x;
  const int wid = tid >> 6, lane = tid & 63;
  const int g = lane >> 4, c = lane & 15;
  const int wr = wid >> 1, wc = wid & 1;  // wave = 64x64 subtile
  const int bm = blockIdx.x, bn = blockIdx.y;

  f32x4 acc[4][4] = {};

  const char* Ag = (const char*)(A + (size_t)bm * 128 * K);
  const char* Bg = (const char*)(Bt + (size_t)bn * 128 * K);
  const int f0 = tid * 16, f1 = f0 + 4096;
  const int r0 = f0 >> 6, cb0 = f0 & 63;
  const int r1 = f1 >> 6;
  const size_t rowbytes = (size_t)K * 2;

  for (int kt = 0; kt < K / 32; ++kt) {
    const size_t koff = (size_t)kt * 64;  // 32 bf16 = 64B
    load16(Ag + (size_t)r0 * rowbytes + koff + cb0, (char*)As + f0);
    load16(Ag + (size_t)r1 * rowbytes + koff + cb0, (char*)As + f1);
    load16(Bg + (size_t)r0 * rowbytes + koff + cb0, (char*)Bs + f0);
    load16(Bg + (size_t)r1 * rowbytes + koff + cb0, (char*)Bs + f1);
    __syncthreads();
    bf16x8 af[4], bfr[4];
#pragma unroll
    for (int mi = 0; mi < 4; ++mi)
      af[mi] = *(const bf16x8*)&As[(wr * 64 + mi * 16 + c) * 32 + g * 8];
#pragma unroll
    for (int ni = 0; ni < 4; ++ni)
      bfr[ni] = *(const bf16x8*)&Bs[(wc * 64 + ni * 16 + c) * 32 + g * 8];
#pragma unroll
    for (int mi = 0; mi < 4; ++mi)
#pragma unroll
      for (int ni = 0; ni < 4; ++ni)
        acc[mi][ni] = MFMA_BF16(af[mi], bfr[ni], acc[mi][ni]);
    __syncthreads();
  }

  // epilogue: C row = (lane>>4)*4 + r, col = lane&15  (per 16x16 frag)
#pragma unroll
  for (int ni = 0; ni < 4; ++ni) {
    const int n_g = bn * 128 + wc * 64 + ni * 16 + c;
    const float bv = bias[n_g];
#pragma unroll
    for (int mi = 0; mi < 4; ++mi) {
#pragma unroll
      for (int r = 0; r < 4; ++r) {
        const int m_g = bm * 128 + wr * 64 + mi * 16 + g * 4 + r;
        const float val = acc[mi][ni][r] + bv;
        if constexpr (MODE == 2) {
          ((float*)out)[(size_t)m_g * DM_ + n_g] = val;
        } else {
          const int b = m_g >> 11, s = m_g & (S_ - 1);
          const int h = n_g >> 6, d = n_g & (D_ - 1);
          size_t idx;
          if constexpr (MODE == 0)
            idx = (((size_t)(b * H_ + h)) * S_ + s) * D_ + d;
          else
            idx = (((size_t)(b * H_ + h)) * D_ + d) * S_ + s;
          ((bf16*)out)[idx] = __float2bfloat16(val);
        }
      }
    }
  }
}

// ---------------- flash attention ----------------
// Q,K: (B,H,S,D) bf16 ; Vt: (B,H,D,S) bf16 ; Aout: (B,S,H*D) bf16
// One wave (64 thr) per block. Each wave handles a BALANCED PAIR of 16-row
// Q tiles: t = blockIdx.x and t = 127 - blockIdx.x  (work = 33 kv-iters for
// every wave -> uniform block durations, no causal-triangle tail).
// l (softmax denom) is accumulated as an extra PV output column via a
// constant ones-B-fragment (no shfl row-sum). exp2-domain softmax with
// defer-max (THR=11.5 log2) skipping most o-rescales.
__global__ __launch_bounds__(64) void flash_attn_kernel(
    const bf16* __restrict__ Q, const bf16* __restrict__ Kg,
    const bf16* __restrict__ Vt, bf16* __restrict__ Aout) {
  __shared__ bf16 P_lds[16][72];  // padded row stride 144B
  const int lane = threadIdx.x;
  const int g = lane >> 4, c = lane & 15;
  const int bh = blockIdx.y;
  const int b = bh >> 4, h = bh & (H_ - 1);

  // ones B-fragment: B[k][col] = (col==0) -> l lands in C column 0
  bf16x8 onesf;
  {
    const short uv = (c == 0) ? (short)0x3f80 : (short)0;
#pragma unroll
    for (int j = 0; j < 8; ++j) onesf[j] = uv;
  }

  const float ALPHA2 = 0.125f * 1.44269504f;  // 1/sqrt(64) * log2(e)
  const float THR2 = 11.5f;                   // defer-max threshold (log2)

#pragma unroll 1
  for (int half = 0; half < 2; ++half) {
    const int t = half ? (127 - (int)blockIdx.x) : (int)blockIdx.x;
    const int ntiles = (t >> 2) + 1;
    const int dtile = t >> 2;  // diagonal kv tile index
    const bf16* Qp = Q + ((size_t)bh * S_ + t * 16) * D_;
    bf16x8 qf0 = *(const bf16x8*)&Qp[c * D_ + g * 8];
    bf16x8 qf1 = *(const bf16x8*)&Qp[c * D_ + 32 + g * 8];

    f32x4 o[4] = {};
    f32x4 lacc = {};
    float m[4];
#pragma unroll
    for (int r = 0; r < 4; ++r) m[r] = -__builtin_inff();
    const int row0 = t * 16 + g * 4;

#pragma unroll 1
    for (int kv = 0; kv < ntiles; ++kv) {
      const bf16* Kp = Kg + ((size_t)bh * S_ + kv * 64) * D_;
      const bf16* Vp = Vt + (size_t)bh * D_ * S_ + kv * 64;

      // issue all K and V fragment loads up front (independent)
      bf16x8 kf[2][4], vf[2][4];
#pragma unroll
      for (int n = 0; n < 4; ++n) {
        kf[0][n] = *(const bf16x8*)&Kp[(n * 16 + c) * D_ + g * 8];
        kf[1][n] = *(const bf16x8*)&Kp[(n * 16 + c) * D_ + 32 + g * 8];
      }
#pragma unroll
      for (int n = 0; n < 4; ++n) {
        vf[0][n] = *(const bf16x8*)&Vp[(size_t)(n * 16 + c) * S_ + g * 8];
        vf[1][n] = *(const bf16x8*)&Vp[(size_t)(n * 16 + c) * S_ + 32 + g * 8];
      }

      f32x4 s[4] = {};
#pragma unroll
      for (int n = 0; n < 4; ++n) {
        s[n] = MFMA_BF16(qf0, kf[0][n], s[n]);
        s[n] = MFMA_BF16(qf1, kf[1][n], s[n]);
      }

      // scale to log2 domain + causal mask (diag tile only)
      float p2[4][4];
      const bool diag = (kv == dtile);
#pragma unroll
      for (int n = 0; n < 4; ++n) {
        const int col = kv * 64 + n * 16 + c;
#pragma unroll
        for (int r = 0; r < 4; ++r) {
          float v = s[n][r] * ALPHA2;
          if (diag && col > row0 + r) v = -__builtin_inff();
          p2[n][r] = v;
        }
      }

      // tile row-max (16-lane butterfly, 4 steps)
      float mt[4];
#pragma unroll
      for (int r = 0; r < 4; ++r)
        mt[r] = fmaxf(fmaxf(p2[0][r], p2[1][r]), fmaxf(p2[2][r], p2[3][r]));
#pragma unroll
      for (int d2 = 1; d2 < 16; d2 <<= 1)
#pragma unroll
        for (int r = 0; r < 4; ++r) mt[r] = fmaxf(mt[r], __shfl_xor(mt[r], d2, 64));

      // defer-max: rescale only when tile max exceeds running max + THR
      bool need = false;
#pragma unroll
      for (int r = 0; r < 4; ++r) need |= (mt[r] > m[r] + THR2);
      if (__any(need)) {
#pragma unroll
        for (int r = 0; r < 4; ++r) {
          const float mnew = fmaxf(m[r], mt[r]);
          const float sc = __builtin_amdgcn_exp2f(m[r] - mnew);
          m[r] = mnew;
          lacc[r] *= sc;
#pragma unroll
          for (int n = 0; n < 4; ++n) o[n][r] *= sc;
        }
      }

      // P = exp2(p2 - m), write to wave-private LDS in A-fragment layout
#pragma unroll
      for (int n = 0; n < 4; ++n)
#pragma unroll
        for (int r = 0; r < 4; ++r) {
          const float pv = __builtin_amdgcn_exp2f(p2[n][r] - m[r]);
          P_lds[g * 4 + r][n * 16 + c] = __float2bfloat16(pv);
        }

      // PV (+ l via ones column)
#pragma unroll
      for (int kk = 0; kk < 2; ++kk) {
        bf16x8 pf = *(const bf16x8*)&P_lds[c][kk * 32 + g * 8];
#pragma unroll
        for (int n = 0; n < 4; ++n) o[n] = MFMA_BF16(pf, vf[kk][n], o[n]);
        lacc = MFMA_BF16(pf, onesf, lacc);
      }
    }

    // l lives in column 0 (lanes c==0); broadcast within each 16-lane group
    float inv[4];
#pragma unroll
    for (int r = 0; r < 4; ++r) {
      const float lv = __shfl(lacc[r], lane & 48, 64);
      inv[r] = 1.f / lv;
    }
#pragma unroll
    for (int n = 0; n < 4; ++n)
#pragma unroll
      for (int r = 0; r < 4; ++r) {
        const size_t row = (size_t)b * S_ + t * 16 + g * 4 + r;
        Aout[row * (H_ * D_) + h * D_ + n * 16 + c] =
            __float2bfloat16(o[n][r] * inv[r]);
      }
  }
}

// ---------------- launcher ----------------

extern "C" void kernel_launch(void* const* d_in, const int* in_sizes, int n_in,
                              void* d_out, int out_size, void* d_ws, size_t ws_size,
                              hipStream_t stream) {
  (void)in_sizes; (void)n_in; (void)out_size; (void)ws_size;
  const float* x  = (const float*)d_in[0];
  const float* Wq = (const float*)d_in[1];
  const float* bq = (const float*)d_in[2];
  const float* Wk = (const float*)d_in[3];
  const float* bk = (const float*)d_in[4];
  const float* Wv = (const float*)d_in[5];
  const float* bv = (const float*)d_in[6];
  const float* Wo = (const float*)d_in[7];
  const float* bo = (const float*)d_in[8];
  float* out = (float*)d_out;

  char* ws = (char*)d_ws;
  bf16* xb  = (bf16*)(ws);                    // 8 MB  (4096x1024 bf16)
  bf16* Wqt = (bf16*)(ws + (8u << 20));       // 2 MB each
  bf16* Wkt = (bf16*)(ws + (10u << 20));
  bf16* Wvt = (bf16*)(ws + (12u << 20));
  bf16* Wot = (bf16*)(ws + (14u << 20));
  bf16* Qb  = (bf16*)(ws + (16u << 20));      // 8 MB  (B,H,S,D)
  bf16* Kb  = (bf16*)(ws + (24u << 20));      // 8 MB
  bf16* Vtb = (bf16*)(ws + (32u << 20));      // 8 MB  (B,H,D,S)
  bf16* Ab  = xb;  // attention out reuses xb (xb dead after V projection)

  cvt_f32_bf16_kernel<<<4096, 256, 0, stream>>>(x, xb, (M_ * DM_) / 4);
  transpose_cvt_kernel<<<dim3(32, 32), 256, 0, stream>>>(Wq, Wqt);
  transpose_cvt_kernel<<<dim3(32, 32), 256, 0, stream>>>(Wk, Wkt);
  transpose_cvt_kernel<<<dim3(32, 32), 256, 0, stream>>>(Wv, Wvt);
  transpose_cvt_kernel<<<dim3(32, 32), 256, 0, stream>>>(Wo, Wot);

  gemm_bt_kernel<0><<<dim3(32, 8), 256, 0, stream>>>(xb, Wqt, bq, (void*)Qb, DM_);
  gemm_bt_kernel<0><<<dim3(32, 8), 256, 0, stream>>>(xb, Wkt, bk, (void*)Kb, DM_);
  gemm_bt_kernel<1><<<dim3(32, 8), 256, 0, stream>>>(xb, Wvt, bv, (void*)Vtb, DM_);

  flash_attn_kernel<<<dim3(64, 32), 64, 0, stream>>>(Qb, Kb, Vtb, Ab);

  gemm_bt_kernel<2><<<dim3(32, 8), 256, 0, stream>>>(Ab, Wot, bo, (void*)out, DM_);
}